// Round 6
// baseline (862.760 us; speedup 1.0000x reference)
//
#include <hip/hip_runtime.h>
#include <math.h>

#define BB 8
#define NN 20000
#define PP 256
#define SSAMP 32
#define CC 256

typedef unsigned short u16;
typedef unsigned int u32;
typedef __attribute__((ext_vector_type(8))) short short8;
typedef __attribute__((ext_vector_type(4))) float f32x4;

__device__ __forceinline__ float b2f(u16 u) {
    union { u32 i; float f; } x; x.i = ((u32)u) << 16; return x.f;
}
__device__ __forceinline__ u16 f2b(float f) {
    union { float f; u32 i; } x; x.f = f;
    u32 i = x.i;
    i += 0x7fffu + ((i >> 16) & 1u);
    return (u16)(i >> 16);
}
__device__ __forceinline__ float rnd_bf(float f) { return b2f(f2b(f)); }
__device__ __forceinline__ float geluf(float x) {
    return 0.5f * x * (1.0f + erff(x * 0.7071067811865476f));
}
__device__ __forceinline__ float siluf(float x) {
    return x / (1.0f + expf(-x));
}
__device__ __forceinline__ f32x4 fz4() { f32x4 z = {0.f,0.f,0.f,0.f}; return z; }

// dtype-adaptive loads: flag=1 -> f32 input, flag=0 -> bf16 input
__device__ __forceinline__ float ldf(const void* p, size_t i, int f32f) {
    return f32f ? ((const float*)p)[i] : b2f(((const u16*)p)[i]);
}
__device__ __forceinline__ u16 ldw(const void* p, size_t i, int f32f) {
    return f32f ? f2b(((const float*)p)[i]) : ((const u16*)p)[i];
}

__device__ __forceinline__ float dotd(const void* wbase, int rowOff, const float* v, int K, int f32f) {
    float acc = 0.f;
    if (f32f) {
        const float* w = (const float*)wbase + rowOff;
        for (int k = 0; k < K; k++) acc += w[k] * v[k];
    } else {
        const u32* w2 = (const u32*)((const u16*)wbase + rowOff);
        for (int k2 = 0; k2 < (K >> 1); k2++) {
            u32 u = w2[k2];
            acc += b2f((u16)(u & 0xffffu)) * v[2*k2];
            acc += b2f((u16)(u >> 16)) * v[2*k2+1];
        }
    }
    return acc;
}

// ---------------- dtype detection ----------------
__global__ void k_detect(const u16* __restrict__ xyzU, int* __restrict__ flagW) {
    int lane = threadIdx.x;            // 64 threads
    u16 u = xyzU[(size_t)lane * 7496]; // even indices, safe under either dtype
    int e = (u >> 7) & 0xFF;
    bool inR = (e >= 0x70) && (e <= 0x85);
    unsigned long long m = __ballot(inR);
    if (lane == 0) *flagW = (__popcll(m) < 48) ? 1 : 0;
}

// ---------------- repack weights -> bf16 blobs, biases -> f32 ----------------
__global__ __launch_bounds__(256) void k_repack(const int* __restrict__ flagp,
        const void* mw0, const void* mb0, const void* mw1, const void* mb1,
        const void* mw2, const void* mb2,
        const void* lw0, const void* lb0, const void* lw1, const void* lb1,
        const void* lw2, const void* lb2,
        u16* __restrict__ W0p, u16* __restrict__ W1p, u16* __restrict__ W2p,
        u16* __restrict__ L0p, u16* __restrict__ L1p, u16* __restrict__ L2p,
        float* __restrict__ biasF) {
    int f32f = *flagp;
    int i = blockIdx.x * 256 + threadIdx.x;
    if (i < 36864) {
        int o = i / 288, c = i % 288;
        u16 v = 0;
        if (c < 256) v = ldw(mw0, o * 259 + 3 + c, f32f);
        else if (c < 259) v = ldw(mw0, o * 259 + (c - 256), f32f);
        W0p[i] = v;
    } else if (i < 53248) {
        W1p[i - 36864] = ldw(mw1, i - 36864, f32f);
    } else if (i < 69632) {
        W2p[i - 53248] = ldw(mw2, i - 53248, f32f);
    } else if (i < 110592) {
        int j = i - 69632;
        int o = j / 160, c = j % 160;
        L0p[j] = (c < 146) ? ldw(lw0, o * 146 + c, f32f) : (u16)0;
    } else if (i < 176128) {
        L1p[i - 110592] = ldw(lw1, i - 110592, f32f);
    } else if (i < 241664) {
        L2p[i - 176128] = ldw(lw2, i - 176128, f32f);
    } else if (i < 242816) {
        int j = i - 241664;
        float v;
        if (j < 128) v = ldf(mb0, j, f32f);
        else if (j < 256) v = ldf(mb1, j - 128, f32f);
        else if (j < 384) v = ldf(mb2, j - 256, f32f);
        else if (j < 640) v = ldf(lb0, j - 384, f32f);
        else if (j < 896) v = ldf(lb1, j - 640, f32f);
        else v = ldf(lb2, j - 896, f32f);
        biasF[j] = v;
    }
}

// ---------------- transpose features [B,C,N] -> bf16 [B,N,C] ----------------
__global__ __launch_bounds__(256) void k_transpose(const int* __restrict__ flagp,
                                                   const void* __restrict__ feat,
                                                   u16* __restrict__ featT) {
    __shared__ u16 tile[64][66];
    int f32f = *flagp;
    int b = blockIdx.z, c0 = blockIdx.y * 64, n0 = blockIdx.x * 64;
    int tx = threadIdx.x, ty = threadIdx.y;
    const size_t fb = (size_t)b * CC * NN;
    for (int i = 0; i < 16; i++) {
        int cl = ty * 16 + i;
        int n = n0 + tx;
        if (n < NN) tile[cl][tx] = ldw(feat, fb + (size_t)(c0 + cl) * NN + n, f32f);
    }
    __syncthreads();
    const size_t tb = (size_t)b * NN * CC;
    for (int i = 0; i < 16; i++) {
        int nl = ty * 16 + i;
        int n = n0 + nl;
        if (n < NN) featT[tb + (size_t)n * CC + c0 + tx] = tile[tx][nl];
    }
}

// ---------------- per-batch time MLPs -> ss[B][256], ssl[B][512] ----------------
__global__ __launch_bounds__(256) void k_time(const int* __restrict__ flagp,
        const void* __restrict__ ts,
        const void* tw0, const void* tb0, const void* tw1, const void* tb1,
        const void* bw, const void* bb,
        const void* tlw0, const void* tlb0, const void* tlw1, const void* tlb1,
        const void* blw, const void* blb,
        float* __restrict__ ssW, float* __restrict__ sslW) {
    __shared__ float s128[128], s256[256], h0[512], temb[512], g0[1024], tembl[1024];
    int f32f = *flagp;
    int b = blockIdx.x, tid = threadIdx.x;
    float t = ldf(ts, b, f32f);
    if (tid < 64) {
        float f = expf(-(float)tid * (logf(10000.0f) / 63.0f));
        float e = t * f;
        s128[tid] = sinf(e); s128[64 + tid] = cosf(e);
    } else if (tid < 192) {
        int j = tid - 64;
        float f = expf(-(float)j * (logf(10000.0f) / 127.0f));
        float e = t * f;
        s256[j] = sinf(e); s256[128 + j] = cosf(e);
    }
    __syncthreads();
    for (int o = tid; o < 512; o += 256)
        h0[o] = geluf(dotd(tw0, o * 128, s128, 128, f32f) + ldf(tb0, o, f32f));
    __syncthreads();
    for (int o = tid; o < 512; o += 256)
        temb[o] = siluf(dotd(tw1, o * 512, h0, 512, f32f) + ldf(tb1, o, f32f));
    __syncthreads();
    { int o = tid; ssW[b * 256 + o] = dotd(bw, o * 512, temb, 512, f32f) + ldf(bb, o, f32f); }
    for (int o = tid; o < 1024; o += 256)
        g0[o] = geluf(dotd(tlw0, o * 256, s256, 256, f32f) + ldf(tlb0, o, f32f));
    __syncthreads();
    for (int o = tid; o < 1024; o += 256)
        tembl[o] = siluf(dotd(tlw1, o * 1024, g0, 1024, f32f) + ldf(tlb1, o, f32f));
    __syncthreads();
    for (int o = tid; o < 512; o += 256)
        sslW[b * 512 + o] = dotd(blw, o * 1024, tembl, 1024, f32f) + ldf(blb, o, f32f);
}

// ---------------- sampler: one wave per proposal ----------------
__global__ __launch_bounds__(256) void k_sample(const int* __restrict__ flagp,
        const void* __restrict__ xyz,
        const void* __restrict__ bsize, const int* __restrict__ inds,
        int* __restrict__ sidx, float* __restrict__ cenW,
        float* __restrict__ outXyz, float* __restrict__ outInds) {
    __shared__ int sBuf[4][SSAMP];
    int f32f = *flagp;
    int wid = threadIdx.x >> 6, lane = threadIdx.x & 63;
    int pg = blockIdx.x * 4 + wid;
    int b = pg >> 8;
    int ind = inds[pg];
    ind = ind < 0 ? 0 : (ind >= NN ? NN - 1 : ind);
    if (lane < SSAMP) sBuf[wid][lane] = 0;
    __syncthreads();
    size_t xb = (size_t)b * NN * 3;
    float cx = ldf(xyz, xb + (size_t)ind * 3 + 0, f32f);
    float cy = ldf(xyz, xb + (size_t)ind * 3 + 1, f32f);
    float cz = ldf(xyz, xb + (size_t)ind * 3 + 2, f32f);
    float hx = 0.5f * ldf(bsize, pg * 3 + 0, f32f);
    float hy = 0.5f * ldf(bsize, pg * 3 + 1, f32f);
    float hz = 0.5f * ldf(bsize, pg * 3 + 2, f32f);
    int cnt = 0;
    for (int n0 = 0; n0 < NN; n0 += 64) {
        int n = n0 + lane;
        bool isin = false;
        if (n < NN) {
            size_t a = xb + (size_t)n * 3;
            float x = ldf(xyz, a, f32f), y = ldf(xyz, a + 1, f32f), z = ldf(xyz, a + 2, f32f);
            isin = (fabsf(x - cx) <= hx) && (fabsf(y - cy) <= hy) && (fabsf(z - cz) <= hz);
        }
        unsigned long long m = __ballot(isin);
        int pre = __popcll(m & ((1ull << lane) - 1ull));
        int pos = cnt + pre;
        if (isin && pos < SSAMP) sBuf[wid][pos] = n;
        cnt += (int)__popcll(m);
        if (cnt >= SSAMP) break;
    }
    int ccap = cnt < SSAMP ? cnt : SSAMP;
    if (ccap < 1) ccap = 1;
    __syncthreads();
    if (lane < SSAMP) sidx[pg * SSAMP + lane] = sBuf[wid][lane % ccap];
    if (lane < 3) {
        float cv = lane == 0 ? cx : (lane == 1 ? cy : cz);
        outXyz[pg * 3 + lane] = cv;          // f32 output
        cenW[pg * 3 + lane] = cv;
    }
    if (lane == 0) outInds[pg] = rnd_bf((float)ind);   // f32 output, bf16-rounded = ref exactly
}

// ---------------- gather + 3-layer MFMA MLP + maxpool + fused FiLM ----------------
__global__ __launch_bounds__(256) void k_mlp1(const int* __restrict__ flagp,
        const u16* __restrict__ featT, const void* __restrict__ feat, int useT,
        const void* __restrict__ xyz, const int* __restrict__ sidx,
        const float* __restrict__ cenW, const float* __restrict__ ssW,
        const u16* __restrict__ W0p, const u16* __restrict__ W1p,
        const u16* __restrict__ W2p, const float* __restrict__ biasF,
        u16* __restrict__ nfB, float* __restrict__ outNF) {
    __shared__ u16 gA[64 * 296];
    __shared__ u16 h1s[64 * 136];
    __shared__ int nrowS[64];
    __shared__ float centS[8];
    int f32f = *flagp;
    int tid = threadIdx.x;
    int pbase = blockIdx.x * 2;
    int b = pbase >> 8;
    if (tid < 64) {
        int n = sidx[pbase * SSAMP + tid];
        nrowS[tid] = n < 0 ? 0 : (n >= NN ? NN - 1 : n);
    }
    if (tid < 6) centS[tid] = cenW[pbase * 3 + tid];
    for (int e = tid; e < 64 * 32; e += 256) {
        int row = e >> 5, c2 = e & 31;
        if (c2 >= 8 && c2 < 28)
            *(u32*)&gA[row * 296 + 256 + (c2 - 8) * 2] = 0u;
    }
    __syncthreads();
    if (useT) {
        for (int e = tid; e < 64 * 32; e += 256) {
            int row = e >> 5, seg = e & 31;
            int n = nrowS[row];
            uint4 v = *(const uint4*)(featT + (size_t)(b * NN + n) * CC + seg * 8);
            *(uint4*)&gA[row * 296 + seg * 8] = v;
        }
    } else {
        int row = tid & 63;
        int n = nrowS[row];
        const size_t fb = (size_t)b * CC * NN;
        int cbase = tid >> 6;
        for (int it = 0; it < 64; it++) {
            int cch = it * 4 + cbase;
            gA[row * 296 + cch] = ldw(feat, fb + (size_t)cch * NN + n, f32f);
        }
    }
    if (tid < 64) {
        int row = tid, q = row >> 5;
        int n = nrowS[row];
        size_t a = ((size_t)b * NN + n) * 3;
        for (int d = 0; d < 3; d++) {
            float gv = ldf(xyz, a + d, f32f) - centS[q * 3 + d];
            gA[row * 296 + 256 + d] = f2b(gv);
        }
    }
    __syncthreads();

    int lane = tid & 63, w = tid >> 6;
    int c15 = lane & 15, kq = lane >> 4;
    f32x4 acc[4][2];

    // ---- layer 1: K=288 ----
    for (int mt = 0; mt < 4; mt++) for (int j = 0; j < 2; j++) acc[mt][j] = fz4();
    for (int ks = 0; ks < 9; ks++) {
        int k0 = ks * 32 + kq * 8;
        short8 af[4];
        for (int mt = 0; mt < 4; mt++)
            af[mt] = *(const short8*)&gA[(mt * 16 + c15) * 296 + k0];
        for (int j = 0; j < 2; j++) {
            int col = w * 32 + j * 16 + c15;
            short8 bf = *(const short8*)(W0p + col * 288 + k0);
            for (int mt = 0; mt < 4; mt++)
                acc[mt][j] = __builtin_amdgcn_mfma_f32_16x16x32_bf16(af[mt], bf, acc[mt][j], 0, 0, 0);
        }
    }
    for (int j = 0; j < 2; j++) {
        int col = w * 32 + j * 16 + c15;
        float bias = biasF[col];
        for (int mt = 0; mt < 4; mt++)
            for (int r = 0; r < 4; r++) {
                float v = acc[mt][j][r] + bias;
                v = v > 0.f ? v : 0.f;
                h1s[(mt * 16 + kq * 4 + r) * 136 + col] = f2b(v);
            }
    }
    __syncthreads();

    // ---- layer 2: K=128, h2 aliases gA ----
    u16* h2s = gA;
    for (int mt = 0; mt < 4; mt++) for (int j = 0; j < 2; j++) acc[mt][j] = fz4();
    for (int ks = 0; ks < 4; ks++) {
        int k0 = ks * 32 + kq * 8;
        short8 af[4];
        for (int mt = 0; mt < 4; mt++)
            af[mt] = *(const short8*)&h1s[(mt * 16 + c15) * 136 + k0];
        for (int j = 0; j < 2; j++) {
            int col = w * 32 + j * 16 + c15;
            short8 bf = *(const short8*)(W1p + col * 128 + k0);
            for (int mt = 0; mt < 4; mt++)
                acc[mt][j] = __builtin_amdgcn_mfma_f32_16x16x32_bf16(af[mt], bf, acc[mt][j], 0, 0, 0);
        }
    }
    __syncthreads();
    for (int j = 0; j < 2; j++) {
        int col = w * 32 + j * 16 + c15;
        float bias = biasF[128 + col];
        for (int mt = 0; mt < 4; mt++)
            for (int r = 0; r < 4; r++) {
                float v = acc[mt][j][r] + bias;
                v = v > 0.f ? v : 0.f;
                h2s[(mt * 16 + kq * 4 + r) * 136 + col] = f2b(v);
            }
    }
    __syncthreads();

    // ---- layer 3: K=128 + maxpool + fused FiLM ----
    for (int mt = 0; mt < 4; mt++) for (int j = 0; j < 2; j++) acc[mt][j] = fz4();
    for (int ks = 0; ks < 4; ks++) {
        int k0 = ks * 32 + kq * 8;
        short8 af[4];
        for (int mt = 0; mt < 4; mt++)
            af[mt] = *(const short8*)&h2s[(mt * 16 + c15) * 136 + k0];
        for (int j = 0; j < 2; j++) {
            int col = w * 32 + j * 16 + c15;
            short8 bf = *(const short8*)(W2p + col * 128 + k0);
            for (int mt = 0; mt < 4; mt++)
                acc[mt][j] = __builtin_amdgcn_mfma_f32_16x16x32_bf16(af[mt], bf, acc[mt][j], 0, 0, 0);
        }
    }
    int pA = pbase & 255, pB = (pbase + 1) & 255;
    float scA = ssW[b * 256 + (pA & 127)] + 1.f, shA = ssW[b * 256 + 128 + (pA & 127)];
    float scB = ssW[b * 256 + (pB & 127)] + 1.f, shB = ssW[b * 256 + 128 + (pB & 127)];
    for (int j = 0; j < 2; j++) {
        int col = w * 32 + j * 16 + c15;
        float bias = biasF[256 + col];
        float mA = 0.f, mB = 0.f;
        for (int mt = 0; mt < 2; mt++)
            for (int r = 0; r < 4; r++) {
                float v = acc[mt][j][r] + bias; v = v > 0.f ? v : 0.f;
                mA = fmaxf(mA, v);
            }
        for (int mt = 2; mt < 4; mt++)
            for (int r = 0; r < 4; r++) {
                float v = acc[mt][j][r] + bias; v = v > 0.f ? v : 0.f;
                mB = fmaxf(mB, v);
            }
        mA = fmaxf(mA, __shfl_xor(mA, 16)); mA = fmaxf(mA, __shfl_xor(mA, 32));
        mB = fmaxf(mB, __shfl_xor(mB, 16)); mB = fmaxf(mB, __shfl_xor(mB, 32));
        if (lane < 16) {
            nfB[(size_t)(pbase + 0) * 128 + col] = f2b(mA);
            nfB[(size_t)(pbase + 1) * 128 + col] = f2b(mB);
            // new_features[b][col][p] = nf*(ss[b,p%128]+1) + ss[b,128+p%128]  (f32 out)
            outNF[((size_t)b * 128 + col) * 256 + pA] = mA * scA + shA;
            outNF[((size_t)b * 128 + col) * 256 + pB] = mB * scB + shB;
        }
    }
}

// ---------------- label MFMA MLP + fused FiLM: 16 proposals/block ----------------
__global__ __launch_bounds__(256) void k_label(const int* __restrict__ flagp,
        const void* __restrict__ blabel,
        const u16* __restrict__ nfB, const u16* __restrict__ L0p,
        const u16* __restrict__ L1p, const u16* __restrict__ L2p,
        const float* __restrict__ biasF, const float* __restrict__ sslW,
        float* __restrict__ outLF) {
    __shared__ u16 liS[16 * 168];
    __shared__ u16 h1L[16 * 264];
    __shared__ u16 h2L[16 * 264];
    int f32f = *flagp;
    int tid = threadIdx.x;
    int pbase = blockIdx.x * 16;
    for (int e = tid; e < 16 * 160; e += 256) {
        int row = e / 160, c = e % 160;
        int pg = pbase + row;
        u16 v = 0;
        if (c < 18) v = ldw(blabel, pg * 18 + c, f32f);
        else if (c < 146) v = nfB[(size_t)pg * 128 + (c - 18)];
        liS[row * 168 + c] = v;
    }
    __syncthreads();
    int lane = tid & 63, w = tid >> 6;
    int c15 = lane & 15, kq = lane >> 4;
    f32x4 acc[4];

    // layer 1: K=160
    for (int j = 0; j < 4; j++) acc[j] = fz4();
    for (int ks = 0; ks < 5; ks++) {
        int k0 = ks * 32 + kq * 8;
        short8 af = *(const short8*)&liS[c15 * 168 + k0];
        for (int j = 0; j < 4; j++) {
            int col = w * 64 + j * 16 + c15;
            short8 bf = *(const short8*)(L0p + col * 160 + k0);
            acc[j] = __builtin_amdgcn_mfma_f32_16x16x32_bf16(af, bf, acc[j], 0, 0, 0);
        }
    }
    for (int j = 0; j < 4; j++) {
        int col = w * 64 + j * 16 + c15;
        float bias = biasF[384 + col];
        for (int r = 0; r < 4; r++) {
            float v = acc[j][r] + bias; v = v > 0.f ? v : 0.f;
            h1L[(kq * 4 + r) * 264 + col] = f2b(v);
        }
    }
    __syncthreads();

    // layer 2: K=256
    for (int j = 0; j < 4; j++) acc[j] = fz4();
    for (int ks = 0; ks < 8; ks++) {
        int k0 = ks * 32 + kq * 8;
        short8 af = *(const short8*)&h1L[c15 * 264 + k0];
        for (int j = 0; j < 4; j++) {
            int col = w * 64 + j * 16 + c15;
            short8 bf = *(const short8*)(L1p + col * 256 + k0);
            acc[j] = __builtin_amdgcn_mfma_f32_16x16x32_bf16(af, bf, acc[j], 0, 0, 0);
        }
    }
    for (int j = 0; j < 4; j++) {
        int col = w * 64 + j * 16 + c15;
        float bias = biasF[640 + col];
        for (int r = 0; r < 4; r++) {
            float v = acc[j][r] + bias; v = v > 0.f ? v : 0.f;
            h2L[(kq * 4 + r) * 264 + col] = f2b(v);
        }
    }
    __syncthreads();

    // layer 3: K=256 + fused FiLM -> outLF (f32)
    for (int j = 0; j < 4; j++) acc[j] = fz4();
    for (int ks = 0; ks < 8; ks++) {
        int k0 = ks * 32 + kq * 8;
        short8 af = *(const short8*)&h2L[c15 * 264 + k0];
        for (int j = 0; j < 4; j++) {
            int col = w * 64 + j * 16 + c15;
            short8 bf = *(const short8*)(L2p + col * 256 + k0);
            acc[j] = __builtin_amdgcn_mfma_f32_16x16x32_bf16(af, bf, acc[j], 0, 0, 0);
        }
    }
    for (int j = 0; j < 4; j++) {
        int col = w * 64 + j * 16 + c15;
        float bias = biasF[896 + col];
        for (int r = 0; r < 4; r++) {
            int pr = pbase + kq * 4 + r;
            int bb2 = pr >> 8, p = pr & 255;
            float v = acc[j][r] + bias; v = v > 0.f ? v : 0.f;
            float sc = sslW[bb2 * 512 + p] + 1.f;
            float sh = sslW[bb2 * 512 + 256 + p];
            outLF[((size_t)bb2 * 256 + col) * 256 + p] = v * sc + sh;
        }
    }
}

extern "C" void kernel_launch(void* const* d_in, const int* in_sizes, int n_in,
                              void* d_out, int out_size, void* d_ws, size_t ws_size,
                              hipStream_t stream) {
    const void* xyz    = d_in[0];
    const void* feat   = d_in[1];
    const void* bsize  = d_in[2];
    const void* blabel = d_in[3];
    const void* ts     = d_in[4];
    const int* inds    = (const int*)d_in[5];
    const void* mw0 = d_in[6];  const void* mb0 = d_in[7];
    const void* mw1 = d_in[8];  const void* mb1 = d_in[9];
    const void* mw2 = d_in[10]; const void* mb2 = d_in[11];
    const void* lw0 = d_in[12]; const void* lb0 = d_in[13];
    const void* lw1 = d_in[14]; const void* lb1 = d_in[15];
    const void* lw2 = d_in[16]; const void* lb2 = d_in[17];
    const void* tw0 = d_in[18]; const void* tb0 = d_in[19];
    const void* tw1 = d_in[20]; const void* tb1 = d_in[21];
    const void* bw  = d_in[22]; const void* bb  = d_in[23];
    const void* tlw0 = d_in[24]; const void* tlb0 = d_in[25];
    const void* tlw1 = d_in[26]; const void* tlb1 = d_in[27];
    const void* blw  = d_in[28]; const void* blb  = d_in[29];

    // d_out is FLOAT32 (reference outputs are f32; harness reads f32, bf16-rounds ref only)
    float* out = (float*)d_out;
    float* outXyz  = out;                 // [0, 6144)
    float* outNF   = out + 6144;          // [6144, 268288)
    float* outLF   = out + 268288;        // [268288, 792576)
    float* outInds = out + 792576;        // [792576, 794624)

    char* ws = (char*)d_ws;
    int*   flag  = (int*)(ws + 0);
    u16*   W0p   = (u16*)(ws + 64);
    u16*   W1p   = (u16*)(ws + 73792);
    u16*   W2p   = (u16*)(ws + 106560);
    u16*   L0p   = (u16*)(ws + 139328);
    u16*   L1p   = (u16*)(ws + 221248);
    u16*   L2p   = (u16*)(ws + 352320);
    float* biasF = (float*)(ws + 483392);
    float* ssW   = (float*)(ws + 488000);
    float* sslW  = (float*)(ws + 496192);
    float* cenW  = (float*)(ws + 512576);
    int*   sidx  = (int*)(ws + 537152);
    u16*   nfB   = (u16*)(ws + 799296);
    u16*   featT = (u16*)(ws + 1323584);
    const size_t NEED_T = 1323584ull + 81920000ull;
    int useT = (ws_size >= NEED_T) ? 1 : 0;

    k_detect<<<dim3(1), dim3(64), 0, stream>>>((const u16*)xyz, flag);
    k_repack<<<dim3(949), dim3(256), 0, stream>>>(flag, mw0, mb0, mw1, mb1, mw2, mb2,
                                                  lw0, lb0, lw1, lb1, lw2, lb2,
                                                  W0p, W1p, W2p, L0p, L1p, L2p, biasF);
    if (useT)
        k_transpose<<<dim3(313, 4, BB), dim3(64, 4), 0, stream>>>(flag, feat, featT);
    k_time<<<dim3(BB), dim3(256), 0, stream>>>(flag, ts, tw0, tb0, tw1, tb1, bw, bb,
                                               tlw0, tlb0, tlw1, tlb1, blw, blb, ssW, sslW);
    k_sample<<<dim3(512), dim3(256), 0, stream>>>(flag, xyz, bsize, inds, sidx, cenW, outXyz, outInds);
    k_mlp1<<<dim3(1024), dim3(256), 0, stream>>>(flag, featT, feat, useT, xyz, sidx, cenW, ssW,
                                                 W0p, W1p, W2p, biasF, nfB, outNF);
    k_label<<<dim3(128), dim3(256), 0, stream>>>(flag, blabel, nfB, L0p, L1p, L2p, biasF, sslW, outLF);
}

// Round 7
// 587.243 us; speedup vs baseline: 1.4692x; 1.4692x over previous
//
#include <hip/hip_runtime.h>
#include <math.h>

#define BB 8
#define NN 20000
#define PP 256
#define SSAMP 32
#define CC 256

typedef unsigned short u16;
typedef unsigned int u32;
typedef __attribute__((ext_vector_type(8))) short short8;
typedef __attribute__((ext_vector_type(4))) float f32x4;

__device__ __forceinline__ float b2f(u16 u) {
    union { u32 i; float f; } x; x.i = ((u32)u) << 16; return x.f;
}
__device__ __forceinline__ u16 f2b(float f) {
    union { float f; u32 i; } x; x.f = f;
    u32 i = x.i;
    i += 0x7fffu + ((i >> 16) & 1u);
    return (u16)(i >> 16);
}
__device__ __forceinline__ float rnd_bf(float f) { return b2f(f2b(f)); }
__device__ __forceinline__ float geluf(float x) {
    return 0.5f * x * (1.0f + erff(x * 0.7071067811865476f));
}
__device__ __forceinline__ float siluf(float x) {
    return x / (1.0f + expf(-x));
}
__device__ __forceinline__ f32x4 fz4() { f32x4 z = {0.f,0.f,0.f,0.f}; return z; }

// dtype-adaptive loads: flag=1 -> f32 input, flag=0 -> bf16 input
__device__ __forceinline__ float ldf(const void* p, size_t i, int f32f) {
    return f32f ? ((const float*)p)[i] : b2f(((const u16*)p)[i]);
}
__device__ __forceinline__ u16 ldw(const void* p, size_t i, int f32f) {
    return f32f ? f2b(((const float*)p)[i]) : ((const u16*)p)[i];
}

// ---------------- dtype detection ----------------
__global__ void k_detect(const u16* __restrict__ xyzU, int* __restrict__ flagW) {
    int lane = threadIdx.x;            // 64 threads
    u16 u = xyzU[(size_t)lane * 7496];
    int e = (u >> 7) & 0xFF;
    bool inR = (e >= 0x70) && (e <= 0x85);
    unsigned long long m = __ballot(inR);
    if (lane == 0) *flagW = (__popcll(m) < 48) ? 1 : 0;
}

// ---------------- repack weights -> bf16 blobs, biases -> f32 ----------------
__global__ __launch_bounds__(256) void k_repack(const int* __restrict__ flagp,
        const void* mw0, const void* mb0, const void* mw1, const void* mb1,
        const void* mw2, const void* mb2,
        const void* lw0, const void* lb0, const void* lw1, const void* lb1,
        const void* lw2, const void* lb2,
        u16* __restrict__ W0p, u16* __restrict__ W1p, u16* __restrict__ W2p,
        u16* __restrict__ L0p, u16* __restrict__ L1p, u16* __restrict__ L2p,
        float* __restrict__ biasF) {
    int f32f = *flagp;
    int i = blockIdx.x * 256 + threadIdx.x;
    if (i < 36864) {
        int o = i / 288, c = i % 288;
        u16 v = 0;
        if (c < 256) v = ldw(mw0, o * 259 + 3 + c, f32f);
        else if (c < 259) v = ldw(mw0, o * 259 + (c - 256), f32f);
        W0p[i] = v;
    } else if (i < 53248) {
        W1p[i - 36864] = ldw(mw1, i - 36864, f32f);
    } else if (i < 69632) {
        W2p[i - 53248] = ldw(mw2, i - 53248, f32f);
    } else if (i < 110592) {
        int j = i - 69632;
        int o = j / 160, c = j % 160;
        L0p[j] = (c < 146) ? ldw(lw0, o * 146 + c, f32f) : (u16)0;
    } else if (i < 176128) {
        L1p[i - 110592] = ldw(lw1, i - 110592, f32f);
    } else if (i < 241664) {
        L2p[i - 176128] = ldw(lw2, i - 176128, f32f);
    } else if (i < 242816) {
        int j = i - 241664;
        float v;
        if (j < 128) v = ldf(mb0, j, f32f);
        else if (j < 256) v = ldf(mb1, j - 128, f32f);
        else if (j < 384) v = ldf(mb2, j - 256, f32f);
        else if (j < 640) v = ldf(lb0, j - 384, f32f);
        else if (j < 896) v = ldf(lb1, j - 640, f32f);
        else v = ldf(lb2, j - 896, f32f);
        biasF[j] = v;
    }
}

// ---------------- transpose features [B,C,N] -> bf16 [.,N,C] ----------------
// b0: source batch offset; dst batch index is blockIdx.z (tier B uses z=1)
__global__ __launch_bounds__(256) void k_transpose(const int* __restrict__ flagp,
                                                   const void* __restrict__ feat,
                                                   u16* __restrict__ featT, int b0) {
    __shared__ u16 tile[64][66];
    int f32f = *flagp;
    int bz = blockIdx.z, c0 = blockIdx.y * 64, n0 = blockIdx.x * 64;
    int b = b0 + bz;
    int tx = threadIdx.x, ty = threadIdx.y;
    const size_t fb = (size_t)b * CC * NN;
    for (int i = 0; i < 16; i++) {
        int cl = ty * 16 + i;
        int n = n0 + tx;
        if (n < NN) tile[cl][tx] = ldw(feat, fb + (size_t)(c0 + cl) * NN + n, f32f);
    }
    __syncthreads();
    const size_t tb = (size_t)bz * NN * CC;
    for (int i = 0; i < 16; i++) {
        int nl = ty * 16 + i;
        int n = n0 + nl;
        if (n < NN) featT[tb + (size_t)n * CC + c0 + tx] = tile[tx][nl];
    }
}

// ---------------- time-MLP layer: wave-per-row GEMV, all 8 batches per wave ----
// ACT: 0=none 1=gelu 2=silu ; SRC: 0=sinusoid128(ts) 1=sinusoid256(ts) 2=global f32 [8][K]
template<int ACT, int SRC>
__global__ __launch_bounds__(256) void k_lin(const int* __restrict__ flagp,
        const void* __restrict__ xin, const void* __restrict__ W,
        const void* __restrict__ bias, float* __restrict__ out, int K, int O) {
    __shared__ float xs[8 * 1024];
    int f32f = *flagp;
    int tid = threadIdx.x;
    if (SRC == 2) {
        const float* X = (const float*)xin;
        for (int i = tid; i < 8 * K; i += 256) xs[i] = X[i];
    } else {
        const int half = (SRC == 0) ? 64 : 128;
        const int dim = half * 2;
        const float cst = (SRC == 0) ? (logf(10000.f) / 63.f) : (logf(10000.f) / 127.f);
        for (int i = tid; i < 8 * dim; i += 256) {
            int b = i / dim, j = i % dim;
            float t = ldf(xin, b, f32f);
            int jj = (j < half) ? j : (j - half);
            float e = t * expf(-(float)jj * cst);
            xs[i] = (j < half) ? sinf(e) : cosf(e);
        }
    }
    __syncthreads();
    int lane = tid & 63, wv = tid >> 6;
    int r = blockIdx.x * 4 + wv;
    if (r >= O) return;
    float acc[8] = {0.f, 0.f, 0.f, 0.f, 0.f, 0.f, 0.f, 0.f};
    for (int k = lane; k < K; k += 64) {
        float wval = ldf(W, (size_t)r * K + k, f32f);
        #pragma unroll
        for (int b = 0; b < 8; b++) acc[b] += wval * xs[b * K + k];
    }
    #pragma unroll
    for (int b = 0; b < 8; b++) {
        acc[b] += __shfl_xor(acc[b], 1);
        acc[b] += __shfl_xor(acc[b], 2);
        acc[b] += __shfl_xor(acc[b], 4);
        acc[b] += __shfl_xor(acc[b], 8);
        acc[b] += __shfl_xor(acc[b], 16);
        acc[b] += __shfl_xor(acc[b], 32);
    }
    if (lane == 0) {
        float bv = ldf(bias, r, f32f);
        #pragma unroll
        for (int b = 0; b < 8; b++) {
            float v = acc[b] + bv;
            if (ACT == 1) v = geluf(v);
            else if (ACT == 2) v = siluf(v);
            out[b * O + r] = v;
        }
    }
}

// ---------------- sampler: one wave per proposal ----------------
__global__ __launch_bounds__(256) void k_sample(const int* __restrict__ flagp,
        const void* __restrict__ xyz,
        const void* __restrict__ bsize, const int* __restrict__ inds,
        int* __restrict__ sidx, float* __restrict__ cenW,
        float* __restrict__ outXyz, float* __restrict__ outInds) {
    __shared__ int sBuf[4][SSAMP];
    int f32f = *flagp;
    int wid = threadIdx.x >> 6, lane = threadIdx.x & 63;
    int pg = blockIdx.x * 4 + wid;
    int b = pg >> 8;
    int ind = inds[pg];
    ind = ind < 0 ? 0 : (ind >= NN ? NN - 1 : ind);
    if (lane < SSAMP) sBuf[wid][lane] = 0;
    __syncthreads();
    size_t xb = (size_t)b * NN * 3;
    float cx = ldf(xyz, xb + (size_t)ind * 3 + 0, f32f);
    float cy = ldf(xyz, xb + (size_t)ind * 3 + 1, f32f);
    float cz = ldf(xyz, xb + (size_t)ind * 3 + 2, f32f);
    float hx = 0.5f * ldf(bsize, pg * 3 + 0, f32f);
    float hy = 0.5f * ldf(bsize, pg * 3 + 1, f32f);
    float hz = 0.5f * ldf(bsize, pg * 3 + 2, f32f);
    int cnt = 0;
    for (int n0 = 0; n0 < NN; n0 += 64) {
        int n = n0 + lane;
        bool isin = false;
        if (n < NN) {
            size_t a = xb + (size_t)n * 3;
            float x = ldf(xyz, a, f32f), y = ldf(xyz, a + 1, f32f), z = ldf(xyz, a + 2, f32f);
            isin = (fabsf(x - cx) <= hx) && (fabsf(y - cy) <= hy) && (fabsf(z - cz) <= hz);
        }
        unsigned long long m = __ballot(isin);
        int pre = __popcll(m & ((1ull << lane) - 1ull));
        int pos = cnt + pre;
        if (isin && pos < SSAMP) sBuf[wid][pos] = n;
        cnt += (int)__popcll(m);
        if (cnt >= SSAMP) break;
    }
    int ccap = cnt < SSAMP ? cnt : SSAMP;
    if (ccap < 1) ccap = 1;
    __syncthreads();
    if (lane < SSAMP) sidx[pg * SSAMP + lane] = sBuf[wid][lane % ccap];
    if (lane < 3) {
        float cv = lane == 0 ? cx : (lane == 1 ? cy : cz);
        outXyz[pg * 3 + lane] = cv;
        cenW[pg * 3 + lane] = cv;
    }
    if (lane == 0) outInds[pg] = rnd_bf((float)ind);
}

// ---------------- gather + 3-layer MFMA MLP + maxpool + fused FiLM ----------------
// tier: 2 = full featT [8*NN,C]; 1 = single-batch featB [NN,C]; 0 = scalar gather
__global__ __launch_bounds__(256) void k_mlp1(const int* __restrict__ flagp,
        const u16* __restrict__ featT, const void* __restrict__ feat,
        int blockOff, int tier,
        const void* __restrict__ xyz, const int* __restrict__ sidx,
        const float* __restrict__ cenW, const float* __restrict__ ssW,
        const u16* __restrict__ W0p, const u16* __restrict__ W1p,
        const u16* __restrict__ W2p, const float* __restrict__ biasF,
        u16* __restrict__ nfB, float* __restrict__ outNF) {
    __shared__ u16 gA[64 * 296];
    __shared__ u16 h1s[64 * 136];
    __shared__ int nrowS[64];
    __shared__ float centS[8];
    int f32f = *flagp;
    int tid = threadIdx.x;
    int pbase = (blockIdx.x + blockOff) * 2;
    int b = pbase >> 8;
    if (tid < 64) {
        int n = sidx[pbase * SSAMP + tid];
        nrowS[tid] = n < 0 ? 0 : (n >= NN ? NN - 1 : n);
    }
    if (tid < 6) centS[tid] = cenW[pbase * 3 + tid];
    for (int e = tid; e < 64 * 32; e += 256) {
        int row = e >> 5, c2 = e & 31;
        if (c2 >= 8 && c2 < 28)
            *(u32*)&gA[row * 296 + 256 + (c2 - 8) * 2] = 0u;
    }
    __syncthreads();
    if (tier >= 1) {
        size_t rowBase = (tier == 2) ? ((size_t)b * NN) : 0;
        for (int e = tid; e < 64 * 32; e += 256) {
            int row = e >> 5, seg = e & 31;
            int n = nrowS[row];
            uint4 v = *(const uint4*)(featT + (rowBase + n) * CC + seg * 8);
            *(uint4*)&gA[row * 296 + seg * 8] = v;
        }
    } else {
        int row = tid & 63;
        int n = nrowS[row];
        const size_t fb = (size_t)b * CC * NN;
        int cbase = tid >> 6;
        for (int it = 0; it < 64; it++) {
            int cch = it * 4 + cbase;
            gA[row * 296 + cch] = ldw(feat, fb + (size_t)cch * NN + n, f32f);
        }
    }
    if (tid < 64) {
        int row = tid, q = row >> 5;
        int n = nrowS[row];
        size_t a = ((size_t)b * NN + n) * 3;
        for (int d = 0; d < 3; d++) {
            float gv = ldf(xyz, a + d, f32f) - centS[q * 3 + d];
            gA[row * 296 + 256 + d] = f2b(gv);
        }
    }
    __syncthreads();

    int lane = tid & 63, w = tid >> 6;
    int c15 = lane & 15, kq = lane >> 4;
    f32x4 acc[4][2];

    // ---- layer 1: K=288 ----
    for (int mt = 0; mt < 4; mt++) for (int j = 0; j < 2; j++) acc[mt][j] = fz4();
    for (int ks = 0; ks < 9; ks++) {
        int k0 = ks * 32 + kq * 8;
        short8 af[4];
        for (int mt = 0; mt < 4; mt++)
            af[mt] = *(const short8*)&gA[(mt * 16 + c15) * 296 + k0];
        for (int j = 0; j < 2; j++) {
            int col = w * 32 + j * 16 + c15;
            short8 bf = *(const short8*)(W0p + col * 288 + k0);
            for (int mt = 0; mt < 4; mt++)
                acc[mt][j] = __builtin_amdgcn_mfma_f32_16x16x32_bf16(af[mt], bf, acc[mt][j], 0, 0, 0);
        }
    }
    for (int j = 0; j < 2; j++) {
        int col = w * 32 + j * 16 + c15;
        float bias = biasF[col];
        for (int mt = 0; mt < 4; mt++)
            for (int r = 0; r < 4; r++) {
                float v = acc[mt][j][r] + bias;
                v = v > 0.f ? v : 0.f;
                h1s[(mt * 16 + kq * 4 + r) * 136 + col] = f2b(v);
            }
    }
    __syncthreads();

    // ---- layer 2: K=128, h2 aliases gA ----
    u16* h2s = gA;
    for (int mt = 0; mt < 4; mt++) for (int j = 0; j < 2; j++) acc[mt][j] = fz4();
    for (int ks = 0; ks < 4; ks++) {
        int k0 = ks * 32 + kq * 8;
        short8 af[4];
        for (int mt = 0; mt < 4; mt++)
            af[mt] = *(const short8*)&h1s[(mt * 16 + c15) * 136 + k0];
        for (int j = 0; j < 2; j++) {
            int col = w * 32 + j * 16 + c15;
            short8 bf = *(const short8*)(W1p + col * 128 + k0);
            for (int mt = 0; mt < 4; mt++)
                acc[mt][j] = __builtin_amdgcn_mfma_f32_16x16x32_bf16(af[mt], bf, acc[mt][j], 0, 0, 0);
        }
    }
    __syncthreads();
    for (int j = 0; j < 2; j++) {
        int col = w * 32 + j * 16 + c15;
        float bias = biasF[128 + col];
        for (int mt = 0; mt < 4; mt++)
            for (int r = 0; r < 4; r++) {
                float v = acc[mt][j][r] + bias;
                v = v > 0.f ? v : 0.f;
                h2s[(mt * 16 + kq * 4 + r) * 136 + col] = f2b(v);
            }
    }
    __syncthreads();

    // ---- layer 3: K=128 + maxpool + fused FiLM ----
    for (int mt = 0; mt < 4; mt++) for (int j = 0; j < 2; j++) acc[mt][j] = fz4();
    for (int ks = 0; ks < 4; ks++) {
        int k0 = ks * 32 + kq * 8;
        short8 af[4];
        for (int mt = 0; mt < 4; mt++)
            af[mt] = *(const short8*)&h2s[(mt * 16 + c15) * 136 + k0];
        for (int j = 0; j < 2; j++) {
            int col = w * 32 + j * 16 + c15;
            short8 bf = *(const short8*)(W2p + col * 128 + k0);
            for (int mt = 0; mt < 4; mt++)
                acc[mt][j] = __builtin_amdgcn_mfma_f32_16x16x32_bf16(af[mt], bf, acc[mt][j], 0, 0, 0);
        }
    }
    int pA = pbase & 255, pB = (pbase + 1) & 255;
    float scA = ssW[b * 256 + (pA & 127)] + 1.f, shA = ssW[b * 256 + 128 + (pA & 127)];
    float scB = ssW[b * 256 + (pB & 127)] + 1.f, shB = ssW[b * 256 + 128 + (pB & 127)];
    for (int j = 0; j < 2; j++) {
        int col = w * 32 + j * 16 + c15;
        float bias = biasF[256 + col];
        float mA = 0.f, mB = 0.f;
        for (int mt = 0; mt < 2; mt++)
            for (int r = 0; r < 4; r++) {
                float v = acc[mt][j][r] + bias; v = v > 0.f ? v : 0.f;
                mA = fmaxf(mA, v);
            }
        for (int mt = 2; mt < 4; mt++)
            for (int r = 0; r < 4; r++) {
                float v = acc[mt][j][r] + bias; v = v > 0.f ? v : 0.f;
                mB = fmaxf(mB, v);
            }
        mA = fmaxf(mA, __shfl_xor(mA, 16)); mA = fmaxf(mA, __shfl_xor(mA, 32));
        mB = fmaxf(mB, __shfl_xor(mB, 16)); mB = fmaxf(mB, __shfl_xor(mB, 32));
        if (lane < 16) {
            nfB[(size_t)(pbase + 0) * 128 + col] = f2b(mA);
            nfB[(size_t)(pbase + 1) * 128 + col] = f2b(mB);
            outNF[((size_t)b * 128 + col) * 256 + pA] = mA * scA + shA;
            outNF[((size_t)b * 128 + col) * 256 + pB] = mB * scB + shB;
        }
    }
}

// ---------------- label MFMA MLP + fused FiLM: 16 proposals/block ----------------
__global__ __launch_bounds__(256) void k_label(const int* __restrict__ flagp,
        const void* __restrict__ blabel,
        const u16* __restrict__ nfB, const u16* __restrict__ L0p,
        const u16* __restrict__ L1p, const u16* __restrict__ L2p,
        const float* __restrict__ biasF, const float* __restrict__ sslW,
        float* __restrict__ outLF) {
    __shared__ u16 liS[16 * 168];
    __shared__ u16 h1L[16 * 264];
    __shared__ u16 h2L[16 * 264];
    int f32f = *flagp;
    int tid = threadIdx.x;
    int pbase = blockIdx.x * 16;
    for (int e = tid; e < 16 * 160; e += 256) {
        int row = e / 160, c = e % 160;
        int pg = pbase + row;
        u16 v = 0;
        if (c < 18) v = ldw(blabel, pg * 18 + c, f32f);
        else if (c < 146) v = nfB[(size_t)pg * 128 + (c - 18)];
        liS[row * 168 + c] = v;
    }
    __syncthreads();
    int lane = tid & 63, w = tid >> 6;
    int c15 = lane & 15, kq = lane >> 4;
    f32x4 acc[4];

    // layer 1: K=160
    for (int j = 0; j < 4; j++) acc[j] = fz4();
    for (int ks = 0; ks < 5; ks++) {
        int k0 = ks * 32 + kq * 8;
        short8 af = *(const short8*)&liS[c15 * 168 + k0];
        for (int j = 0; j < 4; j++) {
            int col = w * 64 + j * 16 + c15;
            short8 bf = *(const short8*)(L0p + col * 160 + k0);
            acc[j] = __builtin_amdgcn_mfma_f32_16x16x32_bf16(af, bf, acc[j], 0, 0, 0);
        }
    }
    for (int j = 0; j < 4; j++) {
        int col = w * 64 + j * 16 + c15;
        float bias = biasF[384 + col];
        for (int r = 0; r < 4; r++) {
            float v = acc[j][r] + bias; v = v > 0.f ? v : 0.f;
            h1L[(kq * 4 + r) * 264 + col] = f2b(v);
        }
    }
    __syncthreads();

    // layer 2: K=256
    for (int j = 0; j < 4; j++) acc[j] = fz4();
    for (int ks = 0; ks < 8; ks++) {
        int k0 = ks * 32 + kq * 8;
        short8 af = *(const short8*)&h1L[c15 * 264 + k0];
        for (int j = 0; j < 4; j++) {
            int col = w * 64 + j * 16 + c15;
            short8 bf = *(const short8*)(L1p + col * 256 + k0);
            acc[j] = __builtin_amdgcn_mfma_f32_16x16x32_bf16(af, bf, acc[j], 0, 0, 0);
        }
    }
    for (int j = 0; j < 4; j++) {
        int col = w * 64 + j * 16 + c15;
        float bias = biasF[640 + col];
        for (int r = 0; r < 4; r++) {
            float v = acc[j][r] + bias; v = v > 0.f ? v : 0.f;
            h2L[(kq * 4 + r) * 264 + col] = f2b(v);
        }
    }
    __syncthreads();

    // layer 3: K=256 + fused FiLM -> outLF (f32)
    for (int j = 0; j < 4; j++) acc[j] = fz4();
    for (int ks = 0; ks < 8; ks++) {
        int k0 = ks * 32 + kq * 8;
        short8 af = *(const short8*)&h2L[c15 * 264 + k0];
        for (int j = 0; j < 4; j++) {
            int col = w * 64 + j * 16 + c15;
            short8 bf = *(const short8*)(L2p + col * 256 + k0);
            acc[j] = __builtin_amdgcn_mfma_f32_16x16x32_bf16(af, bf, acc[j], 0, 0, 0);
        }
    }
    for (int j = 0; j < 4; j++) {
        int col = w * 64 + j * 16 + c15;
        float bias = biasF[896 + col];
        for (int r = 0; r < 4; r++) {
            int pr = pbase + kq * 4 + r;
            int bb2 = pr >> 8, p = pr & 255;
            float v = acc[j][r] + bias; v = v > 0.f ? v : 0.f;
            float sc = sslW[bb2 * 512 + p] + 1.f;
            float sh = sslW[bb2 * 512 + 256 + p];
            outLF[((size_t)bb2 * 256 + col) * 256 + p] = v * sc + sh;
        }
    }
}

extern "C" void kernel_launch(void* const* d_in, const int* in_sizes, int n_in,
                              void* d_out, int out_size, void* d_ws, size_t ws_size,
                              hipStream_t stream) {
    const void* xyz    = d_in[0];
    const void* feat   = d_in[1];
    const void* bsize  = d_in[2];
    const void* blabel = d_in[3];
    const void* ts     = d_in[4];
    const int* inds    = (const int*)d_in[5];
    const void* mw0 = d_in[6];  const void* mb0 = d_in[7];
    const void* mw1 = d_in[8];  const void* mb1 = d_in[9];
    const void* mw2 = d_in[10]; const void* mb2 = d_in[11];
    const void* lw0 = d_in[12]; const void* lb0 = d_in[13];
    const void* lw1 = d_in[14]; const void* lb1 = d_in[15];
    const void* lw2 = d_in[16]; const void* lb2 = d_in[17];
    const void* tw0 = d_in[18]; const void* tb0 = d_in[19];
    const void* tw1 = d_in[20]; const void* tb1 = d_in[21];
    const void* bw  = d_in[22]; const void* bb  = d_in[23];
    const void* tlw0 = d_in[24]; const void* tlb0 = d_in[25];
    const void* tlw1 = d_in[26]; const void* tlb1 = d_in[27];
    const void* blw  = d_in[28]; const void* blb  = d_in[29];

    float* out = (float*)d_out;
    float* outXyz  = out;
    float* outNF   = out + 6144;
    float* outLF   = out + 268288;
    float* outInds = out + 792576;

    char* ws = (char*)d_ws;
    int*   flag  = (int*)(ws + 0);
    u16*   W0p   = (u16*)(ws + 64);
    u16*   W1p   = (u16*)(ws + 73792);
    u16*   W2p   = (u16*)(ws + 106560);
    u16*   L0p   = (u16*)(ws + 139328);
    u16*   L1p   = (u16*)(ws + 221248);
    u16*   L2p   = (u16*)(ws + 352320);
    float* biasF = (float*)(ws + 483392);
    float* ssW   = (float*)(ws + 488000);
    float* sslW  = (float*)(ws + 496192);
    float* cenW  = (float*)(ws + 512576);
    int*   sidx  = (int*)(ws + 537152);
    u16*   nfB   = (u16*)(ws + 799296);
    float* h0W   = (float*)(ws + 1323584);   //  16,384
    float* tembW = (float*)(ws + 1339968);   //  16,384
    float* g0W   = (float*)(ws + 1356352);   //  32,768
    float* temblW= (float*)(ws + 1389120);   //  32,768
    u16*   featT = (u16*)(ws + 1421888);     //  tier A: 81,920,000 / tier B: 10,240,000
    const size_t NEED_A = 1421888ull + 81920000ull;
    const size_t NEED_B = 1421888ull + 10240000ull;
    int tier = (ws_size >= NEED_A) ? 2 : ((ws_size >= NEED_B) ? 1 : 0);

    k_detect<<<dim3(1), dim3(64), 0, stream>>>((const u16*)xyz, flag);
    k_repack<<<dim3(949), dim3(256), 0, stream>>>(flag, mw0, mb0, mw1, mb1, mw2, mb2,
                                                  lw0, lb0, lw1, lb1, lw2, lb2,
                                                  W0p, W1p, W2p, L0p, L1p, L2p, biasF);

    // time-MLP chains (parallel GEMV layers)
    k_lin<1, 0><<<dim3(128), dim3(256), 0, stream>>>(flag, ts, tw0, tb0, h0W, 128, 512);
    k_lin<2, 2><<<dim3(128), dim3(256), 0, stream>>>(flag, h0W, tw1, tb1, tembW, 512, 512);
    k_lin<0, 2><<<dim3(64),  dim3(256), 0, stream>>>(flag, tembW, bw, bb, ssW, 512, 256);
    k_lin<1, 1><<<dim3(256), dim3(256), 0, stream>>>(flag, ts, tlw0, tlb0, g0W, 256, 1024);
    k_lin<2, 2><<<dim3(256), dim3(256), 0, stream>>>(flag, g0W, tlw1, tlb1, temblW, 1024, 1024);
    k_lin<0, 2><<<dim3(128), dim3(256), 0, stream>>>(flag, temblW, blw, blb, sslW, 1024, 512);

    k_sample<<<dim3(512), dim3(256), 0, stream>>>(flag, xyz, bsize, inds, sidx, cenW, outXyz, outInds);

    if (tier == 2) {
        k_transpose<<<dim3(313, 4, BB), dim3(64, 4), 0, stream>>>(flag, feat, featT, 0);
        k_mlp1<<<dim3(1024), dim3(256), 0, stream>>>(flag, featT, feat, 0, 2, xyz, sidx, cenW, ssW,
                                                     W0p, W1p, W2p, biasF, nfB, outNF);
    } else if (tier == 1) {
        for (int b = 0; b < BB; b++) {
            k_transpose<<<dim3(313, 4, 1), dim3(64, 4), 0, stream>>>(flag, feat, featT, b);
            k_mlp1<<<dim3(128), dim3(256), 0, stream>>>(flag, featT, feat, b * 128, 1, xyz, sidx, cenW, ssW,
                                                        W0p, W1p, W2p, biasF, nfB, outNF);
        }
    } else {
        k_mlp1<<<dim3(1024), dim3(256), 0, stream>>>(flag, featT, feat, 0, 0, xyz, sidx, cenW, ssW,
                                                     W0p, W1p, W2p, biasF, nfB, outNF);
    }

    k_label<<<dim3(128), dim3(256), 0, stream>>>(flag, blabel, nfB, L0p, L1p, L2p, biasF, sslW, outLF);
}